// Round 1
// baseline (263.921 us; speedup 1.0000x reference)
//
#include <hip/hip_runtime.h>
#include <math.h>

typedef unsigned long long u64;
typedef unsigned int u32;

#define B_ 2
#define F_ 8
#define P_ 2048
#define T_ 7                   // F-1
#define ROWS (B_*T_*P_)        // 28672

__device__ __forceinline__ u32 ordf(float f) {
  u32 u = __float_as_uint(f);
  return (u & 0x80000000u) ? ~u : (u | 0x80000000u);
}

#define CE(arr,a,b) do { u64 _x=arr[a], _y=arr[b]; bool _s=(_y<_x); arr[a]=_s?_y:_x; arr[b]=_s?_x:_y; } while(0)

// Batcher odd-even mergesort, 8 elements, 19 comparators
__device__ __forceinline__ void sort8(u64* k) {
  CE(k,0,1); CE(k,2,3); CE(k,4,5); CE(k,6,7);
  CE(k,0,2); CE(k,1,3); CE(k,4,6); CE(k,5,7);
  CE(k,1,2); CE(k,5,6);
  CE(k,0,4); CE(k,1,5); CE(k,2,6); CE(k,3,7);
  CE(k,2,4); CE(k,3,5);
  CE(k,1,2); CE(k,3,4); CE(k,5,6);
}

// bitonic input of 16 -> sorted ascending
__device__ __forceinline__ void bmerge16(u64* M) {
#pragma unroll
  for (int st = 8; st >= 1; st >>= 1) {
#pragma unroll
    for (int i = 0; i < 16; ++i) {
      if ((i & st) == 0) { CE(M, i, i + st); }
    }
  }
}

// sorted A[8], B[8] -> sorted M[16]
__device__ __forceinline__ void merge16(const u64* A, const u64* Bv, u64* M) {
#pragma unroll
  for (int i = 0; i < 8; ++i) { M[i] = A[i]; M[8+i] = Bv[7-i]; }
  bmerge16(M);
}

// ---------------- Kernel A: bearing quaternions ----------------
__global__ __launch_bounds__(256) void kA_bearing(const float4* __restrict__ pts,
                                                  float4* __restrict__ bq) {
  int bf = blockIdx.x;                // b*F + f
  const float4* base = pts + (size_t)bf * P_;
  int tid = threadIdx.x;
  float x[8], y[8], z[8];
  float mnx =  INFINITY, mny =  INFINITY, mnz =  INFINITY;
  float mxx = -INFINITY, mxy = -INFINITY, mxz = -INFINITY;
#pragma unroll
  for (int i = 0; i < 8; ++i) {
    float4 v = base[tid + i*256];
    x[i]=v.x; y[i]=v.y; z[i]=v.z;
    mnx=fminf(mnx,v.x); mny=fminf(mny,v.y); mnz=fminf(mnz,v.z);
    mxx=fmaxf(mxx,v.x); mxy=fmaxf(mxy,v.y); mxz=fmaxf(mxz,v.z);
  }
#pragma unroll
  for (int off = 32; off >= 1; off >>= 1) {
    mnx=fminf(mnx,__shfl_xor(mnx,off)); mny=fminf(mny,__shfl_xor(mny,off)); mnz=fminf(mnz,__shfl_xor(mnz,off));
    mxx=fmaxf(mxx,__shfl_xor(mxx,off)); mxy=fmaxf(mxy,__shfl_xor(mxy,off)); mxz=fmaxf(mxz,__shfl_xor(mxz,off));
  }
  __shared__ float red[4][6];
  int wid = tid >> 6, lane = tid & 63;
  if (lane == 0) { red[wid][0]=mnx; red[wid][1]=mny; red[wid][2]=mnz;
                   red[wid][3]=mxx; red[wid][4]=mxy; red[wid][5]=mxz; }
  __syncthreads();
  mnx=fminf(fminf(red[0][0],red[1][0]),fminf(red[2][0],red[3][0]));
  mny=fminf(fminf(red[0][1],red[1][1]),fminf(red[2][1],red[3][1]));
  mnz=fminf(fminf(red[0][2],red[1][2]),fminf(red[2][2],red[3][2]));
  mxx=fmaxf(fmaxf(red[0][3],red[1][3]),fmaxf(red[2][3],red[3][3]));
  mxy=fmaxf(fmaxf(red[0][4],red[1][4]),fmaxf(red[2][4],red[3][4]));
  mxz=fmaxf(fmaxf(red[0][5],red[1][5]),fmaxf(red[2][5],red[3][5]));
  float cx=(mnx+mxx)*0.5f, cy=(mny+mxy)*0.5f, cz=(mnz+mxz)*0.5f;
#pragma unroll
  for (int i = 0; i < 8; ++i) {
    float dx=x[i]-cx, dy=y[i]-cy, dz=z[i]-cz;
    float n = sqrtf(((dx*dx) + dy*dy) + dz*dz);
    n = fmaxf(n, 1e-12f);
    float dxn = dx/n, dyn = dy/n, dzn = dz/n;
    float dotc = fminf(fmaxf(dyn, -0.99999990f), 0.99999990f);
    float half = acosf(dotc) * 0.5f;
    float an = sqrtf(dzn*dzn + dxn*dxn);
    an = fmaxf(an, 1e-12f);
    float axx = dzn/an, axz = (-dxn)/an;
    float s = sinf(half), w = cosf(half);
    bq[(size_t)bf*P_ + tid + i*256] = make_float4(w, axx*s, 0.f, axz*s);
  }
}

// ---------------- Kernel B: forward quaternions ----------------
__global__ __launch_bounds__(256) void kB_qfwd(const float4* __restrict__ bq,
                                               float4* __restrict__ qf) {
  int i = blockIdx.x*256 + threadIdx.x;   // over B*T*P
  int p = i & (P_-1);
  int t = (i >> 11) % T_;
  int b = i / (T_*P_);
  float4 s = bq[((size_t)(b*F_ + t))*P_ + p];       // frame t (src)
  float4 a = bq[((size_t)(b*F_ + t + 1))*P_ + p];   // frame t+1 (tgt)
  float aw=a.x, ax=a.y, ay=a.z, az=a.w;
  float bw=s.x, bx=-s.y, by=-s.z, bz=-s.w;          // conj
  float w  = ((aw*bw - ax*bx) - ay*by) - az*bz;
  float xo = ((aw*bx + ax*bw) + ay*bz) - az*by;
  float yo = ((aw*by - ax*bz) + ay*bw) + az*bx;
  float zo = ((aw*bz + ax*by) - ay*bx) + az*bw;
  float n = sqrtf(((w*w + xo*xo) + yo*yo) + zo*zo);
  n = fmaxf(n, 1e-12f);
  qf[i] = make_float4(w/n, xo/n, yo/n, zo/n);
}

// ---------------- Kernel C: top-40 selection + geo sums ----------------
__device__ __forceinline__ u64 makekey(const float4* __restrict__ pbase, int q,
                                       float px, float py, float pz, float ps) {
  float4 c = pbase[q];
  float dot = fmaf(px, c.x, fmaf(py, c.y, pz*c.z));
  float qs  = fmaf(c.x, c.x, fmaf(c.y, c.y, c.z*c.z));
  float v = (2.f*dot - ps) - qs;       // = reference neg_dist
  u32 ou = ordf(-v);                   // ascending distance order
  return ((u64)ou << 16) | (u32)q;     // lower-index tie-break
}

__global__ __launch_bounds__(64) void kC_select(const float4* __restrict__ pts,
                                                const float4* __restrict__ qf,
                                                float* __restrict__ S) {
  int row  = blockIdx.x;               // (b*7+t)*2048 + p
  int lane = threadIdx.x;
  int p  = row & (P_-1);
  int bt = row >> 11;                  // b*7 + t
  int t  = bt % T_;
  int b  = bt / T_;
  const float4* pbase = pts + (size_t)(b*F_ + t) * P_;
  float4 pw = pbase[p];
  float px = pw.x, py = pw.y, pz = pw.z;
  float ps = fmaf(px,px, fmaf(py,py, pz*pz));

  u64 A[8], Bv[8], M01[16], M23[16];
#pragma unroll
  for (int s = 0; s < 8; ++s) A[s]  = makekey(pbase, s*64 + lane, px,py,pz,ps);
  sort8(A);
#pragma unroll
  for (int s = 0; s < 8; ++s) Bv[s] = makekey(pbase, (8+s)*64 + lane, px,py,pz,ps);
  sort8(Bv);
  merge16(A, Bv, M01);
#pragma unroll
  for (int s = 0; s < 8; ++s) A[s]  = makekey(pbase, (16+s)*64 + lane, px,py,pz,ps);
  sort8(A);
#pragma unroll
  for (int s = 0; s < 8; ++s) Bv[s] = makekey(pbase, (24+s)*64 + lane, px,py,pz,ps);
  sort8(Bv);
  merge16(A, Bv, M23);

  // lane-local sorted top-16 of its 32 candidates
  u64 T16[16];
#pragma unroll
  for (int i = 0; i < 16; ++i) {
    u64 a2 = M01[i], c2 = M23[15-i];
    T16[i] = (c2 < a2) ? c2 : a2;
  }
  bmerge16(T16);

  __shared__ u64 cache[16*64];
#pragma unroll
  for (int j = 0; j < 16; ++j) cache[j*64 + lane] = T16[j];
  // single wave per block: no barrier needed

  u64 h = T16[0];
  int ptr = 0;
  u64 myKey = 0;
  for (int i = 0; i < 40; ++i) {
    u64 m = h;
#pragma unroll
    for (int off = 32; off >= 1; off >>= 1) {
      u64 o = __shfl_xor(m, off);
      if (o < m) m = o;
    }
    if (lane == i) myKey = m;
    if (h == m) {                      // unique keys -> exactly one winner
      ++ptr;
      if (ptr < 16) {
        h = cache[ptr*64 + lane];
      } else {
        // exact refill (P ~ 1e-18): smallest of my 32 keys strictly > m
        u64 best = ~0ull;
#pragma unroll
        for (int s2 = 0; s2 < 32; ++s2) {
          u64 kk = makekey(pbase, s2*64 + lane, px,py,pz,ps);
          if (kk > m && kk < best) best = kk;
        }
        h = best;
      }
    }
  }

  float4 qp = qf[row];
  float geo = 0.f;
  if (lane < 40) {
    int nb = (int)(myKey & 0xffffu);
    float4 nq = qf[(size_t)bt * P_ + nb];
    float d4 = ((qp.x*nq.x + qp.y*nq.y) + qp.z*nq.z) + qp.w*nq.w;
    float dc = fminf(fabsf(d4), 0.99999990f);
    geo = 2.f * acosf(dc);
  }
  float g40 = geo;
  float g15 = (lane < 15) ? geo : 0.f;
  float g5  = (lane < 5)  ? geo : 0.f;
#pragma unroll
  for (int off = 32; off >= 1; off >>= 1) {
    g40 += __shfl_xor(g40, off);
    g15 += __shfl_xor(g15, off);
    g5  += __shfl_xor(g5,  off);
  }
  if (lane == 0) {
    S[0*ROWS + row] = g5  / 5.f;
    S[1*ROWS + row] = g15 / 15.f;
    S[2*ROWS + row] = g40 / 40.f;
  }
}

// ---------------- Kernel E: mean over t, median, output ----------------
__global__ __launch_bounds__(1024) void kE_final(const float* __restrict__ S,
                                                 float* __restrict__ out) {
  int k = blockIdx.x;                  // scale index 0..2
  int tid = threadIdx.x;
  __shared__ float srt[4096];
  const float* Sk = S + (size_t)k * ROWS;
  float m[4];
#pragma unroll
  for (int u = 0; u < 4; ++u) {
    int j = tid + u*1024;              // j = b*2048 + p
    int b = j >> 11, p = j & 2047;
    float acc = 0.f;
#pragma unroll
    for (int t = 0; t < 7; ++t) acc += Sk[(b*7 + t)*2048 + p];
    m[u] = acc / 7.f;
    srt[j] = m[u];
  }
  __syncthreads();
  for (int size = 2; size <= 4096; size <<= 1) {
    for (int stride = size >> 1; stride > 0; stride >>= 1) {
      for (int c = tid; c < 2048; c += 1024) {
        int i = 2*c - (c & (stride - 1));
        int j = i + stride;
        bool up = ((i & size) == 0);
        float a = srt[i], bb = srt[j];
        if ((a > bb) == up) { srt[i] = bb; srt[j] = a; }
      }
      __syncthreads();
    }
  }
  float scale = fmaxf(srt[2047], 1e-6f);   // lower median of 4096
  bool pos = srt[4095] > 0.f;
#pragma unroll
  for (int u = 0; u < 4; ++u) {
    int j = tid + u*1024;
    int b = j >> 11, p = j & 2047;
    float r = pos ? expf(-m[u]/scale) : 1.f;
    float* ob = out + ((size_t)(b*3 + k)*8)*2048 + p;
#pragma unroll
    for (int f = 0; f < 8; ++f) ob[f*2048] = r;
  }
}

extern "C" void kernel_launch(void* const* d_in, const int* in_sizes, int n_in,
                              void* d_out, int out_size, void* d_ws, size_t ws_size,
                              hipStream_t stream) {
  (void)in_sizes; (void)n_in; (void)out_size; (void)ws_size;
  const float4* pts = (const float4*)d_in[0];
  float* ws = (float*)d_ws;
  float4* bq = (float4*)ws;                       // B*F*P*4   = 131072 floats
  float4* qfw = (float4*)(ws + 131072);           // B*T*P*4   = 114688 floats
  float*  S   = ws + 131072 + 114688;             // 3*ROWS    =  86016 floats
  float*  out = (float*)d_out;

  hipLaunchKernelGGL(kA_bearing, dim3(B_*F_), dim3(256), 0, stream, pts, bq);
  hipLaunchKernelGGL(kB_qfwd,    dim3(ROWS/256), dim3(256), 0, stream, bq, qfw);
  hipLaunchKernelGGL(kC_select,  dim3(ROWS), dim3(64), 0, stream, pts, qfw, S);
  hipLaunchKernelGGL(kE_final,   dim3(3), dim3(1024), 0, stream, S, out);
}